// Round 1
// baseline (195.170 us; speedup 1.0000x reference)
//
#include <hip/hip_runtime.h>
#include <math.h>

#define CRF_B 2048
#define CRF_S 4096
#define CRF_T 3
#define CRF_NC 64   // chunks per sequence
#define CRF_C  64   // steps per chunk (NC*C == S)

// ---------------------------------------------------------------------------
// Kernel 1: per-(batch, chunk) thread computes the 3x3 log-semiring transfer
// matrix of its chunk (rows kept as unnormalized products q * 2^C), plus the
// partial gold score and the mask count for its steps.
// Chunk 0 skips step s=0 (handled analytically in the combine kernel).
// ---------------------------------------------------------------------------
__global__ __launch_bounds__(256) void crf_chunk_kernel(
    const float* __restrict__ em,     // B*S*3
    const float* __restrict__ trans,  // 9
    const int*   __restrict__ tags,   // B*S
    const int*   __restrict__ mask,   // B*S
    float* __restrict__ ws_mat,       // B*NC*9
    float* __restrict__ ws_score,     // B*NC
    int*   __restrict__ ws_cnt)       // B*NC
{
    __shared__ float s_tr[9];
    if (threadIdx.x < 9) s_tr[threadIdx.x] = trans[threadIdx.x];
    __syncthreads();

    const int gid = blockIdx.x * blockDim.x + threadIdx.x;   // < B*NC exactly
    const int b = gid >> 6;           // gid / NC
    const int c = gid & 63;           // gid % NC
    const long s0 = (long)c * CRF_C;
    const bool skip0 = (c == 0);

    // exp(transitions), wave-uniform
    float Etr00 = __expf(trans[0]), Etr01 = __expf(trans[1]), Etr02 = __expf(trans[2]);
    float Etr10 = __expf(trans[3]), Etr11 = __expf(trans[4]), Etr12 = __expf(trans[5]);
    float Etr20 = __expf(trans[6]), Etr21 = __expf(trans[7]), Etr22 = __expf(trans[8]);

    // three rows of the chunk matrix, unnormalized: M[r][j] = C_r + log(q_r_j)
    float q00=1.f,q01=0.f,q02=0.f, q10=0.f,q11=1.f,q12=0.f, q20=0.f,q21=0.f,q22=1.f;
    float C0=0.f, C1=0.f, C2=0.f;

    const float4* em4 = (const float4*)(em + ((long)b*CRF_S + s0)*3); // 768B aligned
    const int4*   tg4 = (const int4*)(tags + (long)b*CRF_S + s0);     // 256B aligned
    const int4*   mk4 = (const int4*)(mask + (long)b*CRF_S + s0);

    int p = tags[(long)b*CRF_S + (c ? (s0 - 1) : 0)];  // prev tag entering chunk
    float score = 0.f;
    int cnt = 0;

    auto step = [&](float ev0, float ev1, float ev2, int tv, int mv, bool first) {
        if ((mv != 0) && !first) {
            float X0 = __expf(ev0), X1 = __expf(ev1), X2 = __expf(ev2);
            float n0, n1, n2;
            n0 = q00*Etr00 + q01*Etr10 + q02*Etr20;
            n1 = q00*Etr01 + q01*Etr11 + q02*Etr21;
            n2 = q00*Etr02 + q01*Etr12 + q02*Etr22;
            q00 = n0*X0; q01 = n1*X1; q02 = n2*X2;
            n0 = q10*Etr00 + q11*Etr10 + q12*Etr20;
            n1 = q10*Etr01 + q11*Etr11 + q12*Etr21;
            n2 = q10*Etr02 + q11*Etr12 + q12*Etr22;
            q10 = n0*X0; q11 = n1*X1; q12 = n2*X2;
            n0 = q20*Etr00 + q21*Etr10 + q22*Etr20;
            n1 = q20*Etr01 + q21*Etr11 + q22*Etr21;
            n2 = q20*Etr02 + q21*Etr12 + q22*Etr22;
            q20 = n0*X0; q21 = n1*X1; q22 = n2*X2;
            float ev = (tv == 0) ? ev0 : ((tv == 1) ? ev1 : ev2);
            score += s_tr[p*3 + tv] + ev;
            cnt += 1;
        }
        p = tv;  // reference updates prev unconditionally
    };

    auto renorm = [&](float& qa, float& qb, float& qc, float& Cacc) {
        float mx = fmaxf(fmaxf(qa, qb), qc);                 // > 0 always
        int ex = ((__float_as_int(mx) >> 23) & 0xff) - 127;  // floor(log2(mx))
        float scale = __int_as_float((127 - ex) << 23);      // exact 2^-ex
        qa *= scale; qb *= scale; qc *= scale;
        Cacc += (float)ex * 0.6931471805599453f;
    };

    for (int g = 0; g < CRF_C/4; ++g) {
        float4 ea = em4[3*g + 0];
        float4 eb = em4[3*g + 1];
        float4 ec = em4[3*g + 2];
        int4 t4 = tg4[g];
        int4 m4 = mk4[g];

        step(ea.x, ea.y, ea.z, t4.x, m4.x, skip0 && (g == 0));
        step(ea.w, eb.x, eb.y, t4.y, m4.y, false);
        step(eb.z, eb.w, ec.x, t4.z, m4.z, false);
        step(ec.y, ec.z, ec.w, t4.w, m4.w, false);

        renorm(q00, q01, q02, C0);
        renorm(q10, q11, q12, C1);
        renorm(q20, q21, q22, C2);
    }

    float* M = ws_mat + (size_t)gid * 9;
    M[0] = (q00 > 0.f) ? (C0 + __logf(q00)) : -1e30f;
    M[1] = (q01 > 0.f) ? (C0 + __logf(q01)) : -1e30f;
    M[2] = (q02 > 0.f) ? (C0 + __logf(q02)) : -1e30f;
    M[3] = (q10 > 0.f) ? (C1 + __logf(q10)) : -1e30f;
    M[4] = (q11 > 0.f) ? (C1 + __logf(q11)) : -1e30f;
    M[5] = (q12 > 0.f) ? (C1 + __logf(q12)) : -1e30f;
    M[6] = (q20 > 0.f) ? (C2 + __logf(q20)) : -1e30f;
    M[7] = (q21 > 0.f) ? (C2 + __logf(q21)) : -1e30f;
    M[8] = (q22 > 0.f) ? (C2 + __logf(q22)) : -1e30f;
    ws_score[gid] = score;
    ws_cnt[gid]   = cnt;
}

// ---------------------------------------------------------------------------
// Kernel 2: one thread per batch element. alpha0 = start + em[b,0,:], then
// fold the NC chunk matrices in order with stable logsumexp; assemble score,
// sequence length, end terms; write per-b (log_partition - score).
// ---------------------------------------------------------------------------
__global__ __launch_bounds__(256) void crf_combine_kernel(
    const float* __restrict__ em,
    const float* __restrict__ startt,
    const float* __restrict__ endt,
    const int*   __restrict__ tags,
    const int*   __restrict__ mask,
    const float* __restrict__ ws_mat,
    const float* __restrict__ ws_score,
    const int*   __restrict__ ws_cnt,
    float* __restrict__ perb)
{
    const int b = blockIdx.x * blockDim.x + threadIdx.x;
    if (b >= CRF_B) return;
    const size_t base = (size_t)b * CRF_S;

    float a0 = startt[0] + em[base*3 + 0];
    float a1 = startt[1] + em[base*3 + 1];
    float a2 = startt[2] + em[base*3 + 2];
    float score = 0.f;
    int cnt = (mask[base] != 0) ? 1 : 0;

    const float* M  = ws_mat   + (size_t)b * CRF_NC * 9;
    const float* Sc = ws_score + (size_t)b * CRF_NC;
    const int*   Cn = ws_cnt   + (size_t)b * CRF_NC;

    for (int cch = 0; cch < CRF_NC; ++cch) {
        const float* m = M + cch * 9;
        float m00=m[0],m01=m[1],m02=m[2];
        float m10=m[3],m11=m[4],m12=m[5];
        float m20=m[6],m21=m[7],m22=m[8];

        float x0 = a0 + m00, x1 = a1 + m10, x2 = a2 + m20;
        float mx = fmaxf(fmaxf(x0, x1), x2);
        float n0 = mx + __logf(__expf(x0-mx) + __expf(x1-mx) + __expf(x2-mx));

        x0 = a0 + m01; x1 = a1 + m11; x2 = a2 + m21;
        mx = fmaxf(fmaxf(x0, x1), x2);
        float n1 = mx + __logf(__expf(x0-mx) + __expf(x1-mx) + __expf(x2-mx));

        x0 = a0 + m02; x1 = a1 + m12; x2 = a2 + m22;
        mx = fmaxf(fmaxf(x0, x1), x2);
        float n2 = mx + __logf(__expf(x0-mx) + __expf(x1-mx) + __expf(x2-mx));

        a0 = n0; a1 = n1; a2 = n2;
        score += Sc[cch];
        cnt   += Cn[cch];
    }

    const int tg0 = tags[base];
    score += startt[tg0] + em[base*3 + tg0];
    const int lastidx = (cnt > 0) ? (cnt - 1) : 0;
    score += endt[tags[base + lastidx]];

    float y0 = a0 + endt[0], y1 = a1 + endt[1], y2 = a2 + endt[2];
    float mx = fmaxf(fmaxf(y0, y1), y2);
    float lp = mx + __logf(__expf(y0-mx) + __expf(y1-mx) + __expf(y2-mx));

    perb[b] = lp - score;
}

// ---------------------------------------------------------------------------
// Kernel 3: deterministic mean over B values -> d_out[0]
// ---------------------------------------------------------------------------
__global__ __launch_bounds__(256) void crf_reduce_kernel(
    const float* __restrict__ perb, float* __restrict__ out)
{
    __shared__ float sdata[256];
    const int tid = threadIdx.x;
    float s = 0.f;
    for (int i = tid; i < CRF_B; i += 256) s += perb[i];
    sdata[tid] = s;
    __syncthreads();
    for (int off = 128; off > 0; off >>= 1) {
        if (tid < off) sdata[tid] += sdata[tid + off];
        __syncthreads();
    }
    if (tid == 0) out[0] = sdata[0] * (1.0f / (float)CRF_B);
}

extern "C" void kernel_launch(void* const* d_in, const int* in_sizes, int n_in,
                              void* d_out, int out_size, void* d_ws, size_t ws_size,
                              hipStream_t stream)
{
    const float* em     = (const float*)d_in[0];
    const float* trans  = (const float*)d_in[1];
    const float* startt = (const float*)d_in[2];
    const float* endt   = (const float*)d_in[3];
    const int*   tags   = (const int*)d_in[4];
    const int*   mask   = (const int*)d_in[5];
    float* out = (float*)d_out;

    float* ws_mat   = (float*)d_ws;                               // B*NC*9 f32
    float* ws_score = ws_mat + (size_t)CRF_B * CRF_NC * 9;        // B*NC f32
    int*   ws_cnt   = (int*)(ws_score + (size_t)CRF_B * CRF_NC);  // B*NC i32
    float* perb     = (float*)(ws_cnt + (size_t)CRF_B * CRF_NC);  // B f32

    dim3 blk(256);
    crf_chunk_kernel<<<(CRF_B * CRF_NC) / 256, blk, 0, stream>>>(
        em, trans, tags, mask, ws_mat, ws_score, ws_cnt);
    crf_combine_kernel<<<CRF_B / 256, blk, 0, stream>>>(
        em, startt, endt, tags, mask, ws_mat, ws_score, ws_cnt, perb);
    crf_reduce_kernel<<<1, blk, 0, stream>>>(perb, out);
}

// Round 2
// 69.463 us; speedup vs baseline: 2.8097x; 2.8097x over previous
//
#include <hip/hip_runtime.h>
#include <math.h>

#define CRF_B  2048
#define CRF_S  4096
#define CRF_T  3
#define CRF_NC 256    // chunks per sequence
#define CRF_C  16     // steps per chunk
#define CRF_SEG 16    // chunks folded per combine-a thread

// ---------------------------------------------------------------------------
// Kernel 1: block = one batch row (4 waves x 1024 steps). Each wave stages its
// window into LDS with fully coalesced loads; each lane computes the 3x3
// log-semiring transfer matrix of its 16-step chunk (rows as unnormalized
// products q * e^C), plus partial gold score and mask count.
// ---------------------------------------------------------------------------
__global__ __launch_bounds__(256) void crf_chunk_kernel(
    const float* __restrict__ em,     // B*S*3
    const float* __restrict__ trans,  // 9
    const int*   __restrict__ tags,   // B*S
    const int*   __restrict__ mask,   // B*S
    float* __restrict__ ws_mat,       // [B][NC][9]
    float* __restrict__ ws_score,     // [B][NC]
    int*   __restrict__ ws_cnt)       // [B][NC]
{
    __shared__ float    s_em[4][64 * 49];   // per-wave window, chunk stride 49
    __shared__ unsigned s_tm[4][256];       // packed tag|mask<<2, 1B/step
    __shared__ float    s_tr[9];

    const int tid = threadIdx.x;
    const int w = tid >> 6, l = tid & 63;
    const int b = blockIdx.x;
    const long win0 = (long)b * CRF_S + (long)w * 1024;   // first step of window

    if (tid < 9) s_tr[tid] = trans[tid];

    // ---- stage emissions: 12 float4 per lane, fully coalesced ----
    const float4* g4 = (const float4*)(em + win0 * 3);
    float* se = s_em[w];
    #pragma unroll
    for (int f = 0; f < 12; ++f) {
        float4 v = g4[f * 64 + l];
        int i0 = (f * 64 + l) * 4;          // window-float index
        int ci = i0 / 48;                   // chunk within window
        int r  = i0 - ci * 48;
        float* d = se + ci * 49 + r;
        d[0] = v.x; d[1] = v.y; d[2] = v.z; d[3] = v.w;
    }
    // ---- stage tags+mask packed to bytes ----
    const int4* t4p = (const int4*)(tags + win0);
    const int4* m4p = (const int4*)(mask + win0);
    #pragma unroll
    for (int f = 0; f < 4; ++f) {
        int4 t = t4p[f * 64 + l];
        int4 m = m4p[f * 64 + l];
        unsigned pk =  (unsigned)((t.x & 3) | ((m.x != 0) << 2))
                    | ((unsigned)((t.y & 3) | ((m.y != 0) << 2)) << 8)
                    | ((unsigned)((t.z & 3) | ((m.z != 0) << 2)) << 16)
                    | ((unsigned)((t.w & 3) | ((m.w != 0) << 2)) << 24);
        s_tm[w][f * 64 + l] = pk;
    }
    __syncthreads();   // cross-wave: prev-tag of a window's first chunk

    // ---- per-lane chunk recursion ----
    const int cc = tid;                     // block-wide chunk index 0..255
    float Etr[9];
    #pragma unroll
    for (int k = 0; k < 9; ++k) Etr[k] = __expf(s_tr[k]);

    float q00=1.f,q01=0.f,q02=0.f, q10=0.f,q11=1.f,q12=0.f, q20=0.f,q21=0.f,q22=1.f;
    float C0=0.f, C1=0.f, C2=0.f;

    const float* ce = se + l * 49;
    // packed tag/mask for this chunk: 4 dwords
    unsigned tmw0 = s_tm[w][l*4+0], tmw1 = s_tm[w][l*4+1],
             tmw2 = s_tm[w][l*4+2], tmw3 = s_tm[w][l*4+3];

    const unsigned char* tmb = (const unsigned char*)&s_tm[0][0]; // block-wide bytes
    int p = (cc == 0) ? (int)(tmb[0] & 3) : (int)(tmb[cc * 16 - 1] & 3);

    float score = 0.f;
    int cnt = 0;

    #pragma unroll
    for (int t = 0; t < 16; ++t) {
        float e0 = ce[t*3+0], e1 = ce[t*3+1], e2 = ce[t*3+2];
        unsigned dw = (t < 4) ? tmw0 : (t < 8) ? tmw1 : (t < 12) ? tmw2 : tmw3;
        int byte = (int)((dw >> ((t & 3) * 8)) & 0xffu);
        int tv = byte & 3;
        int mv = byte & 4;
        bool skip = (t == 0) && (cc == 0);   // step 0 handled in combine-b
        if (mv && !skip) {
            float X0 = __expf(e0), X1 = __expf(e1), X2 = __expf(e2);
            float n0, n1, n2;
            n0 = q00*Etr[0] + q01*Etr[3] + q02*Etr[6];
            n1 = q00*Etr[1] + q01*Etr[4] + q02*Etr[7];
            n2 = q00*Etr[2] + q01*Etr[5] + q02*Etr[8];
            q00 = n0*X0; q01 = n1*X1; q02 = n2*X2;
            n0 = q10*Etr[0] + q11*Etr[3] + q12*Etr[6];
            n1 = q10*Etr[1] + q11*Etr[4] + q12*Etr[7];
            n2 = q10*Etr[2] + q11*Etr[5] + q12*Etr[8];
            q10 = n0*X0; q11 = n1*X1; q12 = n2*X2;
            n0 = q20*Etr[0] + q21*Etr[3] + q22*Etr[6];
            n1 = q20*Etr[1] + q21*Etr[4] + q22*Etr[7];
            n2 = q20*Etr[2] + q21*Etr[5] + q22*Etr[8];
            q20 = n0*X0; q21 = n1*X1; q22 = n2*X2;
            float ev = (tv == 0) ? e0 : ((tv == 1) ? e1 : e2);
            score += s_tr[p * 3 + tv] + ev;
            cnt += 1;
        }
        p = tv;
        if ((t & 3) == 3) {   // renorm every 4 steps (exact pow2 scaling)
            float mx, sc; int ex;
            mx = fmaxf(fmaxf(q00, q01), q02);
            ex = ((__float_as_int(mx) >> 23) & 0xff) - 127;
            sc = __int_as_float((127 - ex) << 23);
            q00 *= sc; q01 *= sc; q02 *= sc; C0 += (float)ex * 0.6931471805599453f;
            mx = fmaxf(fmaxf(q10, q11), q12);
            ex = ((__float_as_int(mx) >> 23) & 0xff) - 127;
            sc = __int_as_float((127 - ex) << 23);
            q10 *= sc; q11 *= sc; q12 *= sc; C1 += (float)ex * 0.6931471805599453f;
            mx = fmaxf(fmaxf(q20, q21), q22);
            ex = ((__float_as_int(mx) >> 23) & 0xff) - 127;
            sc = __int_as_float((127 - ex) << 23);
            q20 *= sc; q21 *= sc; q22 *= sc; C2 += (float)ex * 0.6931471805599453f;
        }
    }

    float* M = ws_mat + ((size_t)b * CRF_NC + cc) * 9;
    M[0] = (q00 > 0.f) ? (C0 + __logf(q00)) : -1e30f;
    M[1] = (q01 > 0.f) ? (C0 + __logf(q01)) : -1e30f;
    M[2] = (q02 > 0.f) ? (C0 + __logf(q02)) : -1e30f;
    M[3] = (q10 > 0.f) ? (C1 + __logf(q10)) : -1e30f;
    M[4] = (q11 > 0.f) ? (C1 + __logf(q11)) : -1e30f;
    M[5] = (q12 > 0.f) ? (C1 + __logf(q12)) : -1e30f;
    M[6] = (q20 > 0.f) ? (C2 + __logf(q20)) : -1e30f;
    M[7] = (q21 > 0.f) ? (C2 + __logf(q21)) : -1e30f;
    M[8] = (q22 > 0.f) ? (C2 + __logf(q22)) : -1e30f;
    ws_score[(size_t)b * CRF_NC + cc] = score;
    ws_cnt  [(size_t)b * CRF_NC + cc] = cnt;
}

__device__ __forceinline__ float lse3(float x0, float x1, float x2) {
    float mx = fmaxf(fmaxf(x0, x1), x2);
    return mx + __logf(__expf(x0 - mx) + __expf(x1 - mx) + __expf(x2 - mx));
}

// ---------------------------------------------------------------------------
// Kernel 2a: thread = (b, seg); log-compose 16 consecutive chunk matrices.
// ---------------------------------------------------------------------------
__global__ __launch_bounds__(256) void crf_combine_a(
    const float* __restrict__ ws_mat,
    const float* __restrict__ ws_score,
    const int*   __restrict__ ws_cnt,
    float* __restrict__ seg_mat,     // [B][SEG][9]
    float* __restrict__ seg_score,   // [B][SEG]
    int*   __restrict__ seg_cnt)     // [B][SEG]
{
    const int t = blockIdx.x * blockDim.x + threadIdx.x;   // < B*16
    const int b = t >> 4, seg = t & 15;
    const float* base = ws_mat + ((size_t)b * CRF_NC + seg * CRF_SEG) * 9;

    float R[9];
    #pragma unroll
    for (int i = 0; i < 9; ++i) R[i] = base[i];
    float sc = ws_score[(size_t)b * CRF_NC + seg * CRF_SEG];
    int   cn = ws_cnt  [(size_t)b * CRF_NC + seg * CRF_SEG];

    for (int k = 1; k < CRF_SEG; ++k) {
        const float* m = base + (size_t)k * 9;
        float M0=m[0],M1=m[1],M2=m[2],M3=m[3],M4=m[4],M5=m[5],M6=m[6],M7=m[7],M8=m[8];
        float N[9];
        #pragma unroll
        for (int i = 0; i < 3; ++i) {
            float r0 = R[i*3+0], r1 = R[i*3+1], r2 = R[i*3+2];
            N[i*3+0] = lse3(r0 + M0, r1 + M3, r2 + M6);
            N[i*3+1] = lse3(r0 + M1, r1 + M4, r2 + M7);
            N[i*3+2] = lse3(r0 + M2, r1 + M5, r2 + M8);
        }
        #pragma unroll
        for (int i = 0; i < 9; ++i) R[i] = N[i];
        sc += ws_score[(size_t)b * CRF_NC + seg * CRF_SEG + k];
        cn += ws_cnt  [(size_t)b * CRF_NC + seg * CRF_SEG + k];
    }

    float* o = seg_mat + ((size_t)b * CRF_SEG + seg) * 9;
    #pragma unroll
    for (int i = 0; i < 9; ++i) o[i] = R[i];
    seg_score[(size_t)b * CRF_SEG + seg] = sc;
    seg_cnt  [(size_t)b * CRF_SEG + seg] = cn;
}

// ---------------------------------------------------------------------------
// Kernel 2b: thread = b; fold 16 segment matrices into alpha, assemble score.
// ---------------------------------------------------------------------------
__global__ __launch_bounds__(256) void crf_combine_b(
    const float* __restrict__ em,
    const float* __restrict__ startt,
    const float* __restrict__ endt,
    const int*   __restrict__ tags,
    const int*   __restrict__ mask,
    const float* __restrict__ seg_mat,
    const float* __restrict__ seg_score,
    const int*   __restrict__ seg_cnt,
    float* __restrict__ perb)
{
    const int b = blockIdx.x * blockDim.x + threadIdx.x;
    if (b >= CRF_B) return;
    const size_t base = (size_t)b * CRF_S;

    float a0 = startt[0] + em[base*3 + 0];
    float a1 = startt[1] + em[base*3 + 1];
    float a2 = startt[2] + em[base*3 + 2];
    float score = 0.f;
    int cnt = (mask[base] != 0) ? 1 : 0;

    for (int s = 0; s < CRF_SEG; ++s) {
        const float* m = seg_mat + ((size_t)b * CRF_SEG + s) * 9;
        float n0 = lse3(a0 + m[0], a1 + m[3], a2 + m[6]);
        float n1 = lse3(a0 + m[1], a1 + m[4], a2 + m[7]);
        float n2 = lse3(a0 + m[2], a1 + m[5], a2 + m[8]);
        a0 = n0; a1 = n1; a2 = n2;
        score += seg_score[(size_t)b * CRF_SEG + s];
        cnt   += seg_cnt  [(size_t)b * CRF_SEG + s];
    }

    const int tg0 = tags[base];
    score += startt[tg0] + em[base*3 + tg0];
    const int lastidx = (cnt > 0) ? (cnt - 1) : 0;
    score += endt[tags[base + lastidx]];

    perb[b] = lse3(a0 + endt[0], a1 + endt[1], a2 + endt[2]) - score;
}

// ---------------------------------------------------------------------------
// Kernel 3: deterministic mean over B values.
// ---------------------------------------------------------------------------
__global__ __launch_bounds__(256) void crf_reduce_kernel(
    const float* __restrict__ perb, float* __restrict__ out)
{
    __shared__ float sdata[256];
    const int tid = threadIdx.x;
    float s = 0.f;
    for (int i = tid; i < CRF_B; i += 256) s += perb[i];
    sdata[tid] = s;
    __syncthreads();
    for (int off = 128; off > 0; off >>= 1) {
        if (tid < off) sdata[tid] += sdata[tid + off];
        __syncthreads();
    }
    if (tid == 0) out[0] = sdata[0] * (1.0f / (float)CRF_B);
}

extern "C" void kernel_launch(void* const* d_in, const int* in_sizes, int n_in,
                              void* d_out, int out_size, void* d_ws, size_t ws_size,
                              hipStream_t stream)
{
    const float* em     = (const float*)d_in[0];
    const float* trans  = (const float*)d_in[1];
    const float* startt = (const float*)d_in[2];
    const float* endt   = (const float*)d_in[3];
    const int*   tags   = (const int*)d_in[4];
    const int*   mask   = (const int*)d_in[5];
    float* out = (float*)d_out;

    float* ws_mat    = (float*)d_ws;                                   // B*NC*9
    float* ws_score  = ws_mat   + (size_t)CRF_B * CRF_NC * 9;          // B*NC
    int*   ws_cnt    = (int*)(ws_score + (size_t)CRF_B * CRF_NC);      // B*NC
    float* seg_mat   = (float*)(ws_cnt + (size_t)CRF_B * CRF_NC);      // B*16*9
    float* seg_score = seg_mat  + (size_t)CRF_B * CRF_SEG * 9;         // B*16
    int*   seg_cnt   = (int*)(seg_score + (size_t)CRF_B * CRF_SEG);    // B*16
    float* perb      = (float*)(seg_cnt + (size_t)CRF_B * CRF_SEG);    // B

    dim3 blk(256);
    crf_chunk_kernel<<<CRF_B, blk, 0, stream>>>(
        em, trans, tags, mask, ws_mat, ws_score, ws_cnt);
    crf_combine_a<<<(CRF_B * CRF_SEG) / 256, blk, 0, stream>>>(
        ws_mat, ws_score, ws_cnt, seg_mat, seg_score, seg_cnt);
    crf_combine_b<<<CRF_B / 256, blk, 0, stream>>>(
        em, startt, endt, tags, mask, seg_mat, seg_score, seg_cnt, perb);
    crf_reduce_kernel<<<1, blk, 0, stream>>>(perb, out);
}